// Round 12
// baseline (149351.721 us; speedup 1.0000x reference)
//
#include <hip/hip_runtime.h>
#include <math.h>

// ResRnn on MI355X — round 12: A/B/C/D ablation, barrier-region overlap FIXED
// (regions now 512-dword strided; r11's 256-dword stride let A's leaf 14/15
// counters alias B's gen/root -> free-running race -> inf).
//   A (MODE 0): atomic v-exchange + release-FENCE full-grid barrier (r6-exact)
//               -> writes the REAL out. Canary: absmax == 4.195923e+33.
//   B (MODE 1): A minus fence (vmcnt drain only)   -> scratch out   [fence cost]
//   C (MODE 2): B with per-group 64-block barriers -> scratch out   [span cost]
//   D (MODE 3): no barrier, fixed realistic v state (A's v2047)     [floor]
// u_t = v_{t-1} @ Wc^T + bias + x_t @ W1p^T ; v_t = u + bo*sin(u*inw)

#define WDIM 1024
#define SEQ_N 2048
#define NB 256
#define LDS_BYTES 163840  // 128 KB v-tile + 32 KB reduce -> 1 block/CU

__device__ __forceinline__ double gload(const double* p) {
  unsigned long long v = __hip_atomic_load((const unsigned long long*)p,
                                           __ATOMIC_RELAXED, __HIP_MEMORY_SCOPE_AGENT);
  return __builtin_bit_cast(double, v);
}
__device__ __forceinline__ void gstore(double* p, double d) {
  __hip_atomic_store((unsigned long long*)p, __builtin_bit_cast(unsigned long long, d),
                     __ATOMIC_RELAXED, __HIP_MEMORY_SCOPE_AGENT);
}

// tree barrier; FENCE -> r6 semantics (release fence), else all-wave vmcnt drain
template<bool FENCE>
__device__ __forceinline__ void gbar_t(unsigned* barR, unsigned target, int leaf, int cnt) {
  if constexpr (!FENCE) asm volatile("s_waitcnt vmcnt(0)" ::: "memory");
  __syncthreads();
  if (threadIdx.x == 0) {
    if constexpr (FENCE) __builtin_amdgcn_fence(__ATOMIC_RELEASE, "agent");
    unsigned old = __hip_atomic_fetch_add(&barR[32 + leaf * 16], 1u, __ATOMIC_RELAXED,
                                          __HIP_MEMORY_SCOPE_AGENT);
    if (old + 1u == target * (unsigned)cnt) {
      unsigned r = __hip_atomic_fetch_add(&barR[16], 1u, __ATOMIC_RELAXED,
                                          __HIP_MEMORY_SCOPE_AGENT);
      unsigned leaves = (unsigned)(NB == 256 && cnt == 16 ? 16 : 8);
      if (r + 1u == target * leaves)
        __hip_atomic_store(&barR[0], target, __ATOMIC_RELAXED, __HIP_MEMORY_SCOPE_AGENT);
    }
    while (__hip_atomic_load(&barR[0], __ATOMIC_RELAXED, __HIP_MEMORY_SCOPE_AGENT) < target)
      __builtin_amdgcn_s_sleep(2);
  }
  __syncthreads();
}

// ---- precompute: Wcd[n][k] = sum_j W1[n][j]*W2[j][k] (fp64) ----
__global__ __launch_bounds__(256) void k_gemm_wt(const float* __restrict__ A,
                                                 const float* __restrict__ B,
                                                 double* __restrict__ Wcd) {
  __shared__ float As[32][68];
  __shared__ float Bs[32][68];
  const int tid = threadIdx.x;
  const int tx = tid & 15, ty = tid >> 4;
  const int bx = blockIdx.x, by = blockIdx.y;
  double acc[4][4] = {};
  for (int j0 = 0; j0 < WDIM; j0 += 32) {
    for (int l = tid; l < 64 * 32; l += 256) {
      int r = l >> 5, c = l & 31;
      As[c][r] = A[(by * 64 + r) * WDIM + j0 + c];
    }
    for (int l = tid; l < 32 * 64; l += 256) {
      int r = l >> 6, c = l & 63;
      Bs[r][c] = B[(j0 + r) * WDIM + bx * 64 + c];
    }
    __syncthreads();
#pragma unroll 8
    for (int kk = 0; kk < 32; ++kk) {
      float a[4], bb[4];
      *(float4*)a  = *(const float4*)&As[kk][ty * 4];
      *(float4*)bb = *(const float4*)&Bs[kk][tx * 4];
#pragma unroll
      for (int i = 0; i < 4; ++i)
#pragma unroll
        for (int j = 0; j < 4; ++j) acc[i][j] += (double)a[i] * (double)bb[j];
    }
    __syncthreads();
  }
#pragma unroll
  for (int i = 0; i < 4; ++i)
#pragma unroll
    for (int j = 0; j < 4; ++j)
      Wcd[(size_t)(by * 64 + ty * 4 + i) * WDIM + bx * 64 + tx * 4 + j] = acc[i][j];
}

// ---- precompute: fp64 biases; zero all barrier regions (3072 dwords) ----
__global__ __launch_bounds__(256) void k_bias(const float* __restrict__ W1,
                                              const float* __restrict__ b1,
                                              const float* __restrict__ b2,
                                              const float* __restrict__ s0,
                                              double* __restrict__ b1c,
                                              double* __restrict__ c0, unsigned* bar) {
  if (blockIdx.x < 12) bar[blockIdx.x * 256 + threadIdx.x] = 0u;
  int wave = threadIdx.x >> 6;
  int lane = threadIdx.x & 63;
  int n = blockIdx.x * 4 + wave;
  const float* row = W1 + (size_t)n * WDIM;
  double a1 = 0.0, a2 = 0.0;
  for (int k = lane; k < WDIM; k += 64) {
    double w = (double)row[k];
    a1 += (double)b2[k] * w;
    a2 += (double)s0[k] * w;
  }
#pragma unroll
  for (int off = 32; off; off >>= 1) {
    a1 += __shfl_down(a1, off, 64);
    a2 += __shfl_down(a2, off, 64);
  }
  if (lane == 0) { b1c[n] = (double)b1[n] + a1; c0[n] = (double)b1[n] + a2; }
}

// ---- the recurrent kernel, 4 variants via MODE ----
template<int MODE>
__global__ __launch_bounds__(512, 2) void k_var(
    const float* __restrict__ x, const double* __restrict__ Wcd,
    const float* __restrict__ W1, const double* __restrict__ b1c,
    const double* __restrict__ c0, const float* __restrict__ W2,
    const float* __restrict__ b2, const float* __restrict__ bend,
    const float* __restrict__ inner, const float* __restrict__ outer,
    double* vA, double* vB, float* __restrict__ out, unsigned* bar) {
  extern __shared__ double2 tile[];            // [16*512] double2
  double* red = (double*)(tile + 8192);        // [256*16] double
  const int tid = threadIdx.x;
  const int ks = tid & 31;
  const int bg = (tid >> 5) & 3;
  const int ng = (tid >> 7) & 3;
  const int nt = blockIdx.x & 63, g = blockIdx.x >> 6;
  constexpr bool FENCE = (MODE == 0);

  // barrier region / leaf geometry per mode (regions 512-dword strided!)
  unsigned* barR;
  int leaf, cnt;
  if constexpr (MODE == 0)      { barR = bar;                  leaf = blockIdx.x >> 4;        cnt = 16; }
  else if constexpr (MODE == 1) { barR = bar + 512;            leaf = blockIdx.x >> 4;        cnt = 16; }
  else if constexpr (MODE == 2) { barR = bar + 1024 + g * 512; leaf = (blockIdx.x & 63) >> 3; cnt = 8;  }
  else                          { barR = nullptr; leaf = 0; cnt = 0; }

  if constexpr (MODE != 3) {
    if (tid < 256) gstore(&vA[blockIdx.x * 256 + tid], 0.0);  // zero v_{-1} at IF$
  }

  const double* wrow[4];
  const float* w1row[4];
  const float* w2row[4];
#pragma unroll
  for (int jn = 0; jn < 4; ++jn) {
    int n = nt * 16 + ng * 4 + jn;
    wrow[jn]  = Wcd + (size_t)n * WDIM;
    w1row[jn] = W1 + (size_t)n * WDIM;
    w2row[jn] = W2 + (size_t)n * WDIM;
  }

  const int n_red = nt * 16 + (tid & 15);
  const int b_red = g * 16 + ((tid >> 4) & 15);
  const double bo   = (double)bend[n_red] * (double)outer[n_red];
  const double inw  = (double)inner[n_red];
  const double b1cr = b1c[n_red];
  const double c0r  = c0[n_red];
  const int oswz = (ng * 4) & 15;

  unsigned gent = 0;
  double* vin = vA;
  double* vout = vB;
  if constexpr (MODE != 3) gbar_t<FENCE>(barR, ++gent, leaf, cnt);

  for (int t = 0; t < SEQ_N; ++t) {
    // x & W1 fragment loads first (L2 path; in-order vmcnt returns)
    float2 xv[4][4], wv[4][4];
#pragma unroll
    for (int i = 0; i < 4; ++i) {
      int c2 = i * 32 + ks;
#pragma unroll
      for (int r = 0; r < 4; ++r)
        xv[r][i] = ((const float2*)(x + ((size_t)t * 64 + g * 16 + bg * 4 + r) * 256))[c2];
#pragma unroll
      for (int jn = 0; jn < 4; ++jn)
        wv[jn][i] = ((const float2*)w1row[jn])[c2];
    }
    // batched atomic v loads (IF$)
    double va[16], vb[16];
    {
      const double* srcb = vin + (size_t)(g * 16) * WDIM + tid * 2;
#pragma unroll
      for (int j = 0; j < 16; ++j) {
        va[j] = gload(srcb + (size_t)j * WDIM);
        vb[j] = gload(srcb + (size_t)j * WDIM + 1);
      }
    }
    // x-injection FMA (overlaps v latency)
    double accx[4][4], accy[4][4];
#pragma unroll
    for (int ib = 0; ib < 4; ++ib)
#pragma unroll
      for (int jn = 0; jn < 4; ++jn) { accx[ib][jn] = 0.0; accy[ib][jn] = 0.0; }
#pragma unroll
    for (int i = 0; i < 4; ++i)
#pragma unroll
      for (int jn = 0; jn < 4; ++jn) {
        double wx = (double)wv[jn][i].x, wy = (double)wv[jn][i].y;
        accx[0][jn] += (double)xv[0][i].x * wx; accy[0][jn] += (double)xv[0][i].y * wy;
        accx[1][jn] += (double)xv[1][i].x * wx; accy[1][jn] += (double)xv[1][i].y * wy;
        accx[2][jn] += (double)xv[2][i].x * wx; accy[2][jn] += (double)xv[2][i].y * wy;
        accx[3][jn] += (double)xv[3][i].x * wx; accy[3][jn] += (double)xv[3][i].y * wy;
      }
#pragma unroll
    for (int j = 0; j < 16; ++j)
      tile[j * 512 + tid] = make_double2(va[j], vb[j]);
    __syncthreads();  // S1
#pragma unroll 4
    for (int i = 0; i < 16; ++i) {
      int c2 = i * 32 + ks;
      double2 v0 = tile[(bg * 4 + 0) * 512 + c2];
      double2 v1 = tile[(bg * 4 + 1) * 512 + c2];
      double2 v2 = tile[(bg * 4 + 2) * 512 + c2];
      double2 v3 = tile[(bg * 4 + 3) * 512 + c2];
#pragma unroll
      for (int jn = 0; jn < 4; ++jn) {
        double2 w = ((const double2*)wrow[jn])[c2];
        accx[0][jn] += v0.x * w.x; accy[0][jn] += v0.y * w.y;
        accx[1][jn] += v1.x * w.x; accy[1][jn] += v1.y * w.y;
        accx[2][jn] += v2.x * w.x; accy[2][jn] += v2.y * w.y;
        accx[3][jn] += v3.x * w.x; accy[3][jn] += v3.y * w.y;
      }
    }
#pragma unroll
    for (int ib = 0; ib < 4; ++ib)
#pragma unroll
      for (int jn = 0; jn < 4; ++jn) {
        double p = accx[ib][jn] + accy[ib][jn];
        p += __shfl_xor(p, 16, 64);
        if (ks < 16) {
          int o = (bg * 4 + ib) * 16 + ng * 4 + jn;
          red[o * 16 + (ks ^ ((oswz + jn) & 15))] = p;
        }
      }
    __syncthreads();  // S2
    if (tid < 256) {
      double s = 0.0;
      const int oc = tid & 15;
#pragma unroll
      for (int slc = 0; slc < 16; ++slc)
        s += red[tid * 16 + (slc ^ oc)];
      double u = s + ((MODE != 3 && t == 0) ? c0r : b1cr);
      double gv = u + bo * sin(u * inw);
      gstore(&vout[(size_t)b_red * WDIM + n_red], gv);
    }
    if constexpr (MODE != 3) {
      gbar_t<FENCE>(barR, ++gent, leaf, cnt);
      double* tmp = vin; vin = vout; vout = tmp;
    }
    // MODE 3: no barrier, no swap (vin stays the fixed realistic state)
  }

  // epilogue: stream = v_2047 @ W2^T + b2 (A -> real out; B/C -> scratch)
  if constexpr (MODE != 3) {
    double va[16], vb[16];
    {
      const double* srcb = vin + (size_t)(g * 16) * WDIM + tid * 2;
#pragma unroll
      for (int j = 0; j < 16; ++j) {
        va[j] = gload(srcb + (size_t)j * WDIM);
        vb[j] = gload(srcb + (size_t)j * WDIM + 1);
      }
    }
#pragma unroll
    for (int j = 0; j < 16; ++j)
      tile[j * 512 + tid] = make_double2(va[j], vb[j]);
    __syncthreads();
    double accx[4][4], accy[4][4];
#pragma unroll
    for (int ib = 0; ib < 4; ++ib)
#pragma unroll
      for (int jn = 0; jn < 4; ++jn) { accx[ib][jn] = 0.0; accy[ib][jn] = 0.0; }
#pragma unroll 4
    for (int i = 0; i < 16; ++i) {
      int c2 = i * 32 + ks;
      double2 v0 = tile[(bg * 4 + 0) * 512 + c2];
      double2 v1 = tile[(bg * 4 + 1) * 512 + c2];
      double2 v2 = tile[(bg * 4 + 2) * 512 + c2];
      double2 v3 = tile[(bg * 4 + 3) * 512 + c2];
#pragma unroll
      for (int jn = 0; jn < 4; ++jn) {
        float2 wf = ((const float2*)w2row[jn])[c2];
        double wx = (double)wf.x, wy = (double)wf.y;
        accx[0][jn] += v0.x * wx; accy[0][jn] += v0.y * wy;
        accx[1][jn] += v1.x * wx; accy[1][jn] += v1.y * wy;
        accx[2][jn] += v2.x * wx; accy[2][jn] += v2.y * wy;
        accx[3][jn] += v3.x * wx; accy[3][jn] += v3.y * wy;
      }
    }
#pragma unroll
    for (int ib = 0; ib < 4; ++ib)
#pragma unroll
      for (int jn = 0; jn < 4; ++jn) {
        double p = accx[ib][jn] + accy[ib][jn];
        p += __shfl_xor(p, 16, 64);
        if (ks < 16) {
          int o = (bg * 4 + ib) * 16 + ng * 4 + jn;
          red[o * 16 + (ks ^ ((oswz + jn) & 15))] = p;
        }
      }
    __syncthreads();
    if (tid < 256) {
      double s = 0.0;
      const int oc = tid & 15;
#pragma unroll
      for (int slc = 0; slc < 16; ++slc)
        s += red[tid * 16 + (slc ^ oc)];
      double sv = s + (double)b2[n_red];
      out[4096 + (size_t)b_red * WDIM + n_red] = (float)sv;
      if (n_red < 64) out[(size_t)b_red * 64 + n_red] = (float)sv;
    }
  }
}

extern "C" void kernel_launch(void* const* d_in, const int* in_sizes, int n_in,
                              void* d_out, int out_size, void* d_ws, size_t ws_size,
                              hipStream_t stream) {
  const float* x    = (const float*)d_in[0];
  const float* s0   = (const float*)d_in[1];
  const float* W1   = (const float*)d_in[2];
  const float* b1   = (const float*)d_in[3];
  const float* W2   = (const float*)d_in[4];
  const float* b2   = (const float*)d_in[5];
  const float* bend = (const float*)d_in[6];
  const float* inner= (const float*)d_in[7];
  const float* outer= (const float*)d_in[8];
  double* ws = (double*)d_ws;

  double* Wcd = ws;
  double* b1c = ws + 1048576;
  double* c0  = ws + 1049600;
  double* vA  = ws + 1050624;
  double* vB  = ws + 1116160;
  unsigned* bar = (unsigned*)(ws + 1181696);   // 3072 dwords (= 1536 doubles)
  float* outS  = (float*)(ws + 1183232);       // scratch out (69632 floats)
  float* out = (float*)d_out;

  k_gemm_wt<<<dim3(16, 16), 256, 0, stream>>>(W1, W2, Wcd);
  k_bias<<<256, 256, 0, stream>>>(W1, b1, b2, s0, b1c, c0, bar);

  static bool attr_done = false;
  if (!attr_done) {
    hipFuncSetAttribute((const void*)k_var<0>, hipFuncAttributeMaxDynamicSharedMemorySize, LDS_BYTES);
    hipFuncSetAttribute((const void*)k_var<1>, hipFuncAttributeMaxDynamicSharedMemorySize, LDS_BYTES);
    hipFuncSetAttribute((const void*)k_var<2>, hipFuncAttributeMaxDynamicSharedMemorySize, LDS_BYTES);
    hipFuncSetAttribute((const void*)k_var<3>, hipFuncAttributeMaxDynamicSharedMemorySize, LDS_BYTES);
    attr_done = true;
  }

  void* argsA[] = { (void*)&x, (void*)&Wcd, (void*)&W1, (void*)&b1c, (void*)&c0,
                    (void*)&W2, (void*)&b2, (void*)&bend, (void*)&inner, (void*)&outer,
                    (void*)&vA, (void*)&vB, (void*)&out, (void*)&bar };
  void* argsS[] = { (void*)&x, (void*)&Wcd, (void*)&W1, (void*)&b1c, (void*)&c0,
                    (void*)&W2, (void*)&b2, (void*)&bend, (void*)&inner, (void*)&outer,
                    (void*)&vA, (void*)&vB, (void*)&outS, (void*)&bar };

  // A: r6-exact reference -> REAL out; leaves v_2047 in vA
  if (hipLaunchCooperativeKernel((void*)k_var<0>, dim3(NB), dim3(512), argsA,
                                 LDS_BYTES, stream) != hipSuccess)
    k_var<0><<<dim3(NB), dim3(512), LDS_BYTES, stream>>>(
        x, Wcd, W1, b1c, c0, W2, b2, bend, inner, outer, vA, vB, out, bar);

  // D: barrier-free floor reading fixed realistic vA; plain launch
  k_var<3><<<dim3(NB), dim3(512), LDS_BYTES, stream>>>(
      x, Wcd, W1, b1c, c0, W2, b2, bend, inner, outer, vA, vB, outS, bar);

  // B: no-fence full-grid barrier -> scratch out
  if (hipLaunchCooperativeKernel((void*)k_var<1>, dim3(NB), dim3(512), argsS,
                                 LDS_BYTES, stream) != hipSuccess)
    k_var<1><<<dim3(NB), dim3(512), LDS_BYTES, stream>>>(
        x, Wcd, W1, b1c, c0, W2, b2, bend, inner, outer, vA, vB, outS, bar);

  // C: no-fence per-group (64-block) barriers -> scratch out
  if (hipLaunchCooperativeKernel((void*)k_var<2>, dim3(NB), dim3(512), argsS,
                                 LDS_BYTES, stream) != hipSuccess)
    k_var<2><<<dim3(NB), dim3(512), LDS_BYTES, stream>>>(
        x, Wcd, W1, b1c, c0, W2, b2, bend, inner, outer, vA, vB, outS, bar);
}

// Round 13
// 36376.837 us; speedup vs baseline: 4.1057x; 4.1057x over previous
//
#include <hip/hip_runtime.h>
#include <math.h>

// ResRnn on MI355X — round 13: 2 blocks/CU via 512 blocks x 256 threads x 80 KB LDS.
// r12 ablation: D (no barrier/fence, fixed v) ~= A (full sync) -> step BODY is the
// cost (latency exposure of serial phases), not synchronization. Fix: two
// co-resident blocks per CU from INDEPENDENT batch-group chains (independent
// barriers) -> one block's compute hides the other's stalls. Per-CU traffic and
// per-output fp64 summation order identical to r6 -> absmax canary 4.195923e+33.
// Fallback: proven r6 kernel (256 x 512, 160 KB) if 2/CU occupancy unavailable.
// u_t = v_{t-1} @ Wc^T + bias + x_t @ W1p^T ; v_t = u + bo*sin(u*inw)

#define WDIM 1024
#define SEQ_N 2048
#define LDS8 81920    // 64 KB v-tile + 16 KB reduce (new kernel)
#define LDSL 163840   // legacy kernel

__device__ __forceinline__ double gload(const double* p) {
  unsigned long long v = __hip_atomic_load((const unsigned long long*)p,
                                           __ATOMIC_RELAXED, __HIP_MEMORY_SCOPE_AGENT);
  return __builtin_bit_cast(double, v);
}
__device__ __forceinline__ void gstore(double* p, double d) {
  __hip_atomic_store((unsigned long long*)p, __builtin_bit_cast(unsigned long long, d),
                     __ATOMIC_RELAXED, __HIP_MEMORY_SCOPE_AGENT);
}

// tree barrier, r6 fence semantics. Region: [0]=gen, [16]=root, [32+leaf*16]=leaf.
__device__ __forceinline__ void gbar(unsigned* barR, unsigned target, int leaf,
                                     unsigned perleaf, unsigned leaves) {
  __syncthreads();
  if (threadIdx.x == 0) {
    __builtin_amdgcn_fence(__ATOMIC_RELEASE, "agent");
    unsigned old = __hip_atomic_fetch_add(&barR[32 + leaf * 16], 1u, __ATOMIC_RELAXED,
                                          __HIP_MEMORY_SCOPE_AGENT);
    if (old + 1u == target * perleaf) {
      unsigned r = __hip_atomic_fetch_add(&barR[16], 1u, __ATOMIC_RELAXED,
                                          __HIP_MEMORY_SCOPE_AGENT);
      if (r + 1u == target * leaves)
        __hip_atomic_store(&barR[0], target, __ATOMIC_RELAXED, __HIP_MEMORY_SCOPE_AGENT);
    }
    while (__hip_atomic_load(&barR[0], __ATOMIC_RELAXED, __HIP_MEMORY_SCOPE_AGENT) < target)
      __builtin_amdgcn_s_sleep(2);
  }
  __syncthreads();
}

// ---- precompute: Wcd[n][k] = sum_j W1[n][j]*W2[j][k] (fp64) ----
__global__ __launch_bounds__(256) void k_gemm_wt(const float* __restrict__ A,
                                                 const float* __restrict__ B,
                                                 double* __restrict__ Wcd) {
  __shared__ float As[32][68];
  __shared__ float Bs[32][68];
  const int tid = threadIdx.x;
  const int tx = tid & 15, ty = tid >> 4;
  const int bx = blockIdx.x, by = blockIdx.y;
  double acc[4][4] = {};
  for (int j0 = 0; j0 < WDIM; j0 += 32) {
    for (int l = tid; l < 64 * 32; l += 256) {
      int r = l >> 5, c = l & 31;
      As[c][r] = A[(by * 64 + r) * WDIM + j0 + c];
    }
    for (int l = tid; l < 32 * 64; l += 256) {
      int r = l >> 6, c = l & 63;
      Bs[r][c] = B[(j0 + r) * WDIM + bx * 64 + c];
    }
    __syncthreads();
#pragma unroll 8
    for (int kk = 0; kk < 32; ++kk) {
      float a[4], bb[4];
      *(float4*)a  = *(const float4*)&As[kk][ty * 4];
      *(float4*)bb = *(const float4*)&Bs[kk][tx * 4];
#pragma unroll
      for (int i = 0; i < 4; ++i)
#pragma unroll
        for (int j = 0; j < 4; ++j) acc[i][j] += (double)a[i] * (double)bb[j];
    }
    __syncthreads();
  }
#pragma unroll
  for (int i = 0; i < 4; ++i)
#pragma unroll
    for (int j = 0; j < 4; ++j)
      Wcd[(size_t)(by * 64 + ty * 4 + i) * WDIM + bx * 64 + tx * 4 + j] = acc[i][j];
}

// ---- precompute: fp64 biases; zero barrier regions (16*256 = 4096 dwords) ----
__global__ __launch_bounds__(256) void k_bias(const float* __restrict__ W1,
                                              const float* __restrict__ b1,
                                              const float* __restrict__ b2,
                                              const float* __restrict__ s0,
                                              double* __restrict__ b1c,
                                              double* __restrict__ c0, unsigned* bar) {
  if (blockIdx.x < 16) bar[blockIdx.x * 256 + threadIdx.x] = 0u;
  int wave = threadIdx.x >> 6;
  int lane = threadIdx.x & 63;
  int n = blockIdx.x * 4 + wave;
  const float* row = W1 + (size_t)n * WDIM;
  double a1 = 0.0, a2 = 0.0;
  for (int k = lane; k < WDIM; k += 64) {
    double w = (double)row[k];
    a1 += (double)b2[k] * w;
    a2 += (double)s0[k] * w;
  }
#pragma unroll
  for (int off = 32; off; off >>= 1) {
    a1 += __shfl_down(a1, off, 64);
    a2 += __shfl_down(a2, off, 64);
  }
  if (lane == 0) { b1c[n] = (double)b1[n] + a1; c0[n] = (double)b1[n] + a2; }
}

// ================= NEW: 512 blocks x 256 threads, 8b x 16n per block =================
// blk = g*64 + nt (g<8: 8 batch rows each; nt<64). thread: ks=tid&31, bg=(tid>>5)&1,
// ng=tid>>6. Per thread: 4b x 4n acc over k-slice {i*32+ks} — identical inner loop
// and summation order to r6 -> bit-identical trajectory.
// LDS: tile[8][512] double2 (64 KB) + red[128][16] double (16 KB).
// Barrier: per-group (64 blocks), 8 leaves x 8 arrivals, region bar + g*512.
__global__ __launch_bounds__(256, 2) void k_main8(
    const float* __restrict__ x, const double* __restrict__ Wcd,
    const float* __restrict__ W1, const double* __restrict__ b1c,
    const double* __restrict__ c0, const float* __restrict__ W2,
    const float* __restrict__ b2, const float* __restrict__ bend,
    const float* __restrict__ inner, const float* __restrict__ outer,
    double* vA, double* vB, float* __restrict__ out, unsigned* bar) {
  extern __shared__ double2 tile[];            // [8*512] double2
  double* red = (double*)(tile + 4096);        // [128*16] double
  const int tid = threadIdx.x;
  const int ks = tid & 31;
  const int bg = (tid >> 5) & 1;
  const int ng = tid >> 6;
  const int nt = blockIdx.x & 63, g = blockIdx.x >> 6;
  const int leaf = nt >> 3;
  unsigned* barG = bar + g * 512;

  if (tid < 128) vA[blockIdx.x * 128 + tid] = 0.0;  // zero v_{-1}; first fence flushes

  const double* wrow[4];
  const float* w1row[4];
  const float* w2row[4];
#pragma unroll
  for (int jn = 0; jn < 4; ++jn) {
    int n = nt * 16 + ng * 4 + jn;
    wrow[jn]  = Wcd + (size_t)n * WDIM;
    w1row[jn] = W1 + (size_t)n * WDIM;
    w2row[jn] = W2 + (size_t)n * WDIM;
  }

  const int n_red = nt * 16 + (tid & 15);
  const int b_red = g * 8 + ((tid >> 4) & 7);   // valid for tid<128 reducers
  const double bo   = (double)bend[n_red] * (double)outer[n_red];
  const double inw  = (double)inner[n_red];
  const double b1cr = b1c[n_red];
  const double c0r  = c0[n_red];
  const int oswz = (ng * 4) & 15;

  unsigned gent = 0;
  double* vin = vA;
  double* vout = vB;
  gbar(barG, ++gent, leaf, 8u, 8u);

  for (int t = 0; t < SEQ_N; ++t) {
    // x & W1 fragment loads first (L2 path; in-order vmcnt returns)
    float2 xv[4][4], wv[4][4];
#pragma unroll
    for (int i = 0; i < 4; ++i) {
      int c2 = i * 32 + ks;
#pragma unroll
      for (int r = 0; r < 4; ++r)
        xv[r][i] = ((const float2*)(x + ((size_t)t * 64 + g * 8 + bg * 4 + r) * 256))[c2];
#pragma unroll
      for (int jn = 0; jn < 4; ++jn)
        wv[jn][i] = ((const float2*)w1row[jn])[c2];
    }
    // batched atomic v loads (IF$): 16 double2 per thread, rows r = idx>>9
    double va[16], vb[16];
    {
#pragma unroll
      for (int j = 0; j < 16; ++j) {
        int idx = j * 256 + tid;
        int r = idx >> 9, c2 = idx & 511;
        const double* s = vin + (size_t)(g * 8 + r) * WDIM + c2 * 2;
        va[j] = gload(s); vb[j] = gload(s + 1);
      }
    }
    // x-injection FMA (overlaps v latency)
    double accx[4][4], accy[4][4];
#pragma unroll
    for (int ib = 0; ib < 4; ++ib)
#pragma unroll
      for (int jn = 0; jn < 4; ++jn) { accx[ib][jn] = 0.0; accy[ib][jn] = 0.0; }
#pragma unroll
    for (int i = 0; i < 4; ++i)
#pragma unroll
      for (int jn = 0; jn < 4; ++jn) {
        double wx = (double)wv[jn][i].x, wy = (double)wv[jn][i].y;
        accx[0][jn] += (double)xv[0][i].x * wx; accy[0][jn] += (double)xv[0][i].y * wy;
        accx[1][jn] += (double)xv[1][i].x * wx; accy[1][jn] += (double)xv[1][i].y * wy;
        accx[2][jn] += (double)xv[2][i].x * wx; accy[2][jn] += (double)xv[2][i].y * wy;
        accx[3][jn] += (double)xv[3][i].x * wx; accy[3][jn] += (double)xv[3][i].y * wy;
      }
#pragma unroll
    for (int j = 0; j < 16; ++j) {
      int idx = j * 256 + tid;
      tile[idx] = make_double2(va[j], vb[j]);  // tile[r*512 + c2], linear
    }
    __syncthreads();  // S1
#pragma unroll 4
    for (int i = 0; i < 16; ++i) {
      int c2 = i * 32 + ks;
      double2 v0 = tile[(bg * 4 + 0) * 512 + c2];
      double2 v1 = tile[(bg * 4 + 1) * 512 + c2];
      double2 v2 = tile[(bg * 4 + 2) * 512 + c2];
      double2 v3 = tile[(bg * 4 + 3) * 512 + c2];
#pragma unroll
      for (int jn = 0; jn < 4; ++jn) {
        double2 w = ((const double2*)wrow[jn])[c2];
        accx[0][jn] += v0.x * w.x; accy[0][jn] += v0.y * w.y;
        accx[1][jn] += v1.x * w.x; accy[1][jn] += v1.y * w.y;
        accx[2][jn] += v2.x * w.x; accy[2][jn] += v2.y * w.y;
        accx[3][jn] += v3.x * w.x; accy[3][jn] += v3.y * w.y;
      }
    }
#pragma unroll
    for (int ib = 0; ib < 4; ++ib)
#pragma unroll
      for (int jn = 0; jn < 4; ++jn) {
        double p = accx[ib][jn] + accy[ib][jn];
        p += __shfl_xor(p, 16, 64);
        if (ks < 16) {
          int o = (bg * 4 + ib) * 16 + ng * 4 + jn;
          red[o * 16 + (ks ^ ((oswz + jn) & 15))] = p;
        }
      }
    __syncthreads();  // S2
    if (tid < 128) {
      double s = 0.0;
      const int oc = tid & 15;
#pragma unroll
      for (int slc = 0; slc < 16; ++slc)
        s += red[tid * 16 + (slc ^ oc)];
      double u = s + (t == 0 ? c0r : b1cr);
      double gv = u + bo * sin(u * inw);
      gstore(&vout[(size_t)b_red * WDIM + n_red], gv);
    }
    gbar(barG, ++gent, leaf, 8u, 8u);
    double* tmp = vin; vin = vout; vout = tmp;
  }

  // epilogue: stream = v_2047 @ W2^T + b2
  {
    double va[16], vb[16];
#pragma unroll
    for (int j = 0; j < 16; ++j) {
      int idx = j * 256 + tid;
      int r = idx >> 9, c2 = idx & 511;
      const double* s = vin + (size_t)(g * 8 + r) * WDIM + c2 * 2;
      va[j] = gload(s); vb[j] = gload(s + 1);
    }
#pragma unroll
    for (int j = 0; j < 16; ++j)
      tile[j * 256 + tid] = make_double2(va[j], vb[j]);
    __syncthreads();
    double accx[4][4], accy[4][4];
#pragma unroll
    for (int ib = 0; ib < 4; ++ib)
#pragma unroll
      for (int jn = 0; jn < 4; ++jn) { accx[ib][jn] = 0.0; accy[ib][jn] = 0.0; }
#pragma unroll 4
    for (int i = 0; i < 16; ++i) {
      int c2 = i * 32 + ks;
      double2 v0 = tile[(bg * 4 + 0) * 512 + c2];
      double2 v1 = tile[(bg * 4 + 1) * 512 + c2];
      double2 v2 = tile[(bg * 4 + 2) * 512 + c2];
      double2 v3 = tile[(bg * 4 + 3) * 512 + c2];
#pragma unroll
      for (int jn = 0; jn < 4; ++jn) {
        float2 wf = ((const float2*)w2row[jn])[c2];
        double wx = (double)wf.x, wy = (double)wf.y;
        accx[0][jn] += v0.x * wx; accy[0][jn] += v0.y * wy;
        accx[1][jn] += v1.x * wx; accy[1][jn] += v1.y * wy;
        accx[2][jn] += v2.x * wx; accy[2][jn] += v2.y * wy;
        accx[3][jn] += v3.x * wx; accy[3][jn] += v3.y * wy;
      }
    }
#pragma unroll
    for (int ib = 0; ib < 4; ++ib)
#pragma unroll
      for (int jn = 0; jn < 4; ++jn) {
        double p = accx[ib][jn] + accy[ib][jn];
        p += __shfl_xor(p, 16, 64);
        if (ks < 16) {
          int o = (bg * 4 + ib) * 16 + ng * 4 + jn;
          red[o * 16 + (ks ^ ((oswz + jn) & 15))] = p;
        }
      }
    __syncthreads();
    if (tid < 128) {
      double s = 0.0;
      const int oc = tid & 15;
#pragma unroll
      for (int slc = 0; slc < 16; ++slc)
        s += red[tid * 16 + (slc ^ oc)];
      double sv = s + (double)b2[n_red];
      out[4096 + (size_t)b_red * WDIM + n_red] = (float)sv;
      if (n_red < 64) out[(size_t)b_red * 64 + n_red] = (float)sv;
    }
  }
}

// ================= LEGACY fallback: r6-exact (256 x 512, 160 KB) =================
__global__ __launch_bounds__(512, 2) void k_main(
    const float* __restrict__ x, const double* __restrict__ Wcd,
    const float* __restrict__ W1, const double* __restrict__ b1c,
    const double* __restrict__ c0, const float* __restrict__ W2,
    const float* __restrict__ b2, const float* __restrict__ bend,
    const float* __restrict__ inner, const float* __restrict__ outer,
    double* vA, double* vB, float* __restrict__ out, unsigned* bar) {
  extern __shared__ double2 tile[];
  double* red = (double*)(tile + 8192);
  const int tid = threadIdx.x;
  const int ks = tid & 31;
  const int bg = (tid >> 5) & 3;
  const int ng = (tid >> 7) & 3;
  const int nt = blockIdx.x & 63, g = blockIdx.x >> 6;
  const int leaf = blockIdx.x >> 4;

  if (tid < 256) vA[blockIdx.x * 256 + tid] = 0.0;

  const double* wrow[4];
  const float* w1row[4];
  const float* w2row[4];
#pragma unroll
  for (int jn = 0; jn < 4; ++jn) {
    int n = nt * 16 + ng * 4 + jn;
    wrow[jn]  = Wcd + (size_t)n * WDIM;
    w1row[jn] = W1 + (size_t)n * WDIM;
    w2row[jn] = W2 + (size_t)n * WDIM;
  }
  const int n_red = nt * 16 + (tid & 15);
  const int b_red = g * 16 + ((tid >> 4) & 15);
  const double bo   = (double)bend[n_red] * (double)outer[n_red];
  const double inw  = (double)inner[n_red];
  const double b1cr = b1c[n_red];
  const double c0r  = c0[n_red];
  const int oswz = (ng * 4) & 15;

  unsigned gent = 0;
  double* vin = vA;
  double* vout = vB;
  gbar(bar, ++gent, leaf, 16u, 16u);

  for (int t = 0; t < SEQ_N; ++t) {
    float2 xv[4][4], wv[4][4];
#pragma unroll
    for (int i = 0; i < 4; ++i) {
      int c2 = i * 32 + ks;
#pragma unroll
      for (int r = 0; r < 4; ++r)
        xv[r][i] = ((const float2*)(x + ((size_t)t * 64 + g * 16 + bg * 4 + r) * 256))[c2];
#pragma unroll
      for (int jn = 0; jn < 4; ++jn)
        wv[jn][i] = ((const float2*)w1row[jn])[c2];
    }
    double va[16], vb[16];
    {
      const double* srcb = vin + (size_t)(g * 16) * WDIM + tid * 2;
#pragma unroll
      for (int j = 0; j < 16; ++j) {
        va[j] = gload(srcb + (size_t)j * WDIM);
        vb[j] = gload(srcb + (size_t)j * WDIM + 1);
      }
    }
    double accx[4][4], accy[4][4];
#pragma unroll
    for (int ib = 0; ib < 4; ++ib)
#pragma unroll
      for (int jn = 0; jn < 4; ++jn) { accx[ib][jn] = 0.0; accy[ib][jn] = 0.0; }
#pragma unroll
    for (int i = 0; i < 4; ++i)
#pragma unroll
      for (int jn = 0; jn < 4; ++jn) {
        double wx = (double)wv[jn][i].x, wy = (double)wv[jn][i].y;
        accx[0][jn] += (double)xv[0][i].x * wx; accy[0][jn] += (double)xv[0][i].y * wy;
        accx[1][jn] += (double)xv[1][i].x * wx; accy[1][jn] += (double)xv[1][i].y * wy;
        accx[2][jn] += (double)xv[2][i].x * wx; accy[2][jn] += (double)xv[2][i].y * wy;
        accx[3][jn] += (double)xv[3][i].x * wx; accy[3][jn] += (double)xv[3][i].y * wy;
      }
#pragma unroll
    for (int j = 0; j < 16; ++j)
      tile[j * 512 + tid] = make_double2(va[j], vb[j]);
    __syncthreads();
#pragma unroll 4
    for (int i = 0; i < 16; ++i) {
      int c2 = i * 32 + ks;
      double2 v0 = tile[(bg * 4 + 0) * 512 + c2];
      double2 v1 = tile[(bg * 4 + 1) * 512 + c2];
      double2 v2 = tile[(bg * 4 + 2) * 512 + c2];
      double2 v3 = tile[(bg * 4 + 3) * 512 + c2];
#pragma unroll
      for (int jn = 0; jn < 4; ++jn) {
        double2 w = ((const double2*)wrow[jn])[c2];
        accx[0][jn] += v0.x * w.x; accy[0][jn] += v0.y * w.y;
        accx[1][jn] += v1.x * w.x; accy[1][jn] += v1.y * w.y;
        accx[2][jn] += v2.x * w.x; accy[2][jn] += v2.y * w.y;
        accx[3][jn] += v3.x * w.x; accy[3][jn] += v3.y * w.y;
      }
    }
#pragma unroll
    for (int ib = 0; ib < 4; ++ib)
#pragma unroll
      for (int jn = 0; jn < 4; ++jn) {
        double p = accx[ib][jn] + accy[ib][jn];
        p += __shfl_xor(p, 16, 64);
        if (ks < 16) {
          int o = (bg * 4 + ib) * 16 + ng * 4 + jn;
          red[o * 16 + (ks ^ ((oswz + jn) & 15))] = p;
        }
      }
    __syncthreads();
    if (tid < 256) {
      double s = 0.0;
      const int oc = tid & 15;
#pragma unroll
      for (int slc = 0; slc < 16; ++slc)
        s += red[tid * 16 + (slc ^ oc)];
      double u = s + (t == 0 ? c0r : b1cr);
      double gv = u + bo * sin(u * inw);
      gstore(&vout[(size_t)b_red * WDIM + n_red], gv);
    }
    gbar(bar, ++gent, leaf, 16u, 16u);
    double* tmp = vin; vin = vout; vout = tmp;
  }
  {
    double va[16], vb[16];
    {
      const double* srcb = vin + (size_t)(g * 16) * WDIM + tid * 2;
#pragma unroll
      for (int j = 0; j < 16; ++j) {
        va[j] = gload(srcb + (size_t)j * WDIM);
        vb[j] = gload(srcb + (size_t)j * WDIM + 1);
      }
    }
#pragma unroll
    for (int j = 0; j < 16; ++j)
      tile[j * 512 + tid] = make_double2(va[j], vb[j]);
    __syncthreads();
    double accx[4][4], accy[4][4];
#pragma unroll
    for (int ib = 0; ib < 4; ++ib)
#pragma unroll
      for (int jn = 0; jn < 4; ++jn) { accx[ib][jn] = 0.0; accy[ib][jn] = 0.0; }
#pragma unroll 4
    for (int i = 0; i < 16; ++i) {
      int c2 = i * 32 + ks;
      double2 v0 = tile[(bg * 4 + 0) * 512 + c2];
      double2 v1 = tile[(bg * 4 + 1) * 512 + c2];
      double2 v2 = tile[(bg * 4 + 2) * 512 + c2];
      double2 v3 = tile[(bg * 4 + 3) * 512 + c2];
#pragma unroll
      for (int jn = 0; jn < 4; ++jn) {
        float2 wf = ((const float2*)w2row[jn])[c2];
        double wx = (double)wf.x, wy = (double)wf.y;
        accx[0][jn] += v0.x * wx; accy[0][jn] += v0.y * wy;
        accx[1][jn] += v1.x * wx; accy[1][jn] += v1.y * wy;
        accx[2][jn] += v2.x * wx; accy[2][jn] += v2.y * wy;
        accx[3][jn] += v3.x * wx; accy[3][jn] += v3.y * wy;
      }
    }
#pragma unroll
    for (int ib = 0; ib < 4; ++ib)
#pragma unroll
      for (int jn = 0; jn < 4; ++jn) {
        double p = accx[ib][jn] + accy[ib][jn];
        p += __shfl_xor(p, 16, 64);
        if (ks < 16) {
          int o = (bg * 4 + ib) * 16 + ng * 4 + jn;
          red[o * 16 + (ks ^ ((oswz + jn) & 15))] = p;
        }
      }
    __syncthreads();
    if (tid < 256) {
      double s = 0.0;
      const int oc = tid & 15;
#pragma unroll
      for (int slc = 0; slc < 16; ++slc)
        s += red[tid * 16 + (slc ^ oc)];
      double sv = s + (double)b2[n_red];
      out[4096 + (size_t)b_red * WDIM + n_red] = (float)sv;
      if (n_red < 64) out[(size_t)b_red * 64 + n_red] = (float)sv;
    }
  }
}

extern "C" void kernel_launch(void* const* d_in, const int* in_sizes, int n_in,
                              void* d_out, int out_size, void* d_ws, size_t ws_size,
                              hipStream_t stream) {
  const float* x    = (const float*)d_in[0];
  const float* s0   = (const float*)d_in[1];
  const float* W1   = (const float*)d_in[2];
  const float* b1   = (const float*)d_in[3];
  const float* W2   = (const float*)d_in[4];
  const float* b2   = (const float*)d_in[5];
  const float* bend = (const float*)d_in[6];
  const float* inner= (const float*)d_in[7];
  const float* outer= (const float*)d_in[8];
  double* ws = (double*)d_ws;

  double* Wcd = ws;
  double* b1c = ws + 1048576;
  double* c0  = ws + 1049600;
  double* vA  = ws + 1050624;
  double* vB  = ws + 1116160;
  unsigned* bar = (unsigned*)(ws + 1181696);  // 4096 dwords: 8 groups x 512 stride
  float* out = (float*)d_out;

  k_gemm_wt<<<dim3(16, 16), 256, 0, stream>>>(W1, W2, Wcd);
  k_bias<<<256, 256, 0, stream>>>(W1, b1, b2, s0, b1c, c0, bar);

  static bool attr_done = false;
  if (!attr_done) {
    hipFuncSetAttribute((const void*)k_main8, hipFuncAttributeMaxDynamicSharedMemorySize, LDS8);
    hipFuncSetAttribute((const void*)k_main,  hipFuncAttributeMaxDynamicSharedMemorySize, LDSL);
    attr_done = true;
  }

  void* args[] = { (void*)&x, (void*)&Wcd, (void*)&W1, (void*)&b1c, (void*)&c0,
                   (void*)&W2, (void*)&b2, (void*)&bend, (void*)&inner, (void*)&outer,
                   (void*)&vA, (void*)&vB, (void*)&out, (void*)&bar };

  int maxB8 = 0;
  hipError_t q8 = hipOccupancyMaxActiveBlocksPerMultiprocessor(&maxB8, k_main8, 256, LDS8);
  if (q8 == hipSuccess && maxB8 >= 2) {
    // 512 blocks at 2/CU fill all 256 CUs by pigeonhole -> co-residency guaranteed
    if (hipLaunchCooperativeKernel((void*)k_main8, dim3(512), dim3(256), args,
                                   LDS8, stream) != hipSuccess)
      k_main8<<<dim3(512), dim3(256), LDS8, stream>>>(
          x, Wcd, W1, b1c, c0, W2, b2, bend, inner, outer, vA, vB, out, bar);
  } else {
    // proven r6 config
    if (hipLaunchCooperativeKernel((void*)k_main, dim3(256), dim3(512), args,
                                   LDSL, stream) != hipSuccess)
      k_main<<<dim3(256), dim3(512), LDSL, stream>>>(
          x, Wcd, W1, b1c, c0, W2, b2, bend, inner, outer, vA, vB, out, bar);
  }
}